// Round 6
// baseline (418.264 us; speedup 1.0000x reference)
//
#include <hip/hip_runtime.h>
#include <hip/hip_cooperative_groups.h>

namespace cg = cooperative_groups;

#define N_NODES 50000
#define N_EDGES 800000
#define IN_F    128
#define HEADS   8
#define OUT_F   16
#define N_TILES ((N_NODES + 63) / 64)   // 64-row tiles for node_proj

typedef unsigned short u16;
typedef __attribute__((ext_vector_type(8))) short bf16x8;   // 4 VGPRs
typedef __attribute__((ext_vector_type(4))) float f32x4;

__device__ __forceinline__ float bf2f(u16 u) {
    return __uint_as_float(((unsigned)u) << 16);
}
__device__ __forceinline__ u16 f2bf(float f) {
    unsigned u = __float_as_uint(f);
    unsigned r = 0x7fffu + ((u >> 16) & 1u);
    return (u16)((u + r) >> 16);
}
// dtype-adaptive float load: bf=true -> buffer is bf16, else fp32
__device__ __forceinline__ float ldf(const void* p, int i, bool bf) {
    return bf ? bf2f(((const u16*)p)[i]) : ((const float*)p)[i];
}

// ==================================================================== build
// One cooperative kernel: probe+zero -> node_proj(MFMA)+hist -> alloc ->
// scatter. Grid-stride phases, grid.sync() between dependent phases.
// LDS 34.8 KB -> 4 blocks/CU; launch_bounds(256,4) caps VGPR at 128.
#define WT_STRIDE 136   // bf16 units; 272 B rows: 16B-aligned, 2-way banks only
__global__ __launch_bounds__(256, 4) void build(
    const void* __restrict__ h, const void* __restrict__ Wn,
    const void* __restrict__ a_srcp, const void* __restrict__ a_dstp,
    const int* __restrict__ ei, const void* __restrict__ ef,
    int* __restrict__ flag, int* __restrict__ total,
    u16* __restrict__ ht, float* __restrict__ s_src, float* __restrict__ s_dst,
    int* __restrict__ counts, int* __restrict__ seg_off,
    int* __restrict__ cursor, int2* __restrict__ edge_s)
{
    cg::grid_group grid = cg::this_grid();
    const int tid  = threadIdx.x;
    const int gidx = blockIdx.x * 256 + tid;
    const int gsz  = gridDim.x * 256;

    // ---- phase 0: zero counts/total + dtype probe -------------------------
    for (int i = gidx; i < N_NODES; i += gsz) counts[i] = 0;
    if (gidx == 0) *total = 0;
    if (blockIdx.x == 0 && tid < 64) {
        const u16* u = (const u16*)h;
        int good = 0;
        #pragma unroll
        for (int j = 0; j < 2; ++j) {
            int e = (u[tid * 2 + j] >> 7) & 0xFF;
            good += (e >= 90 && e <= 141) ? 1 : 0;
        }
        #pragma unroll
        for (int o = 32; o; o >>= 1) good += __shfl_down(good, o, 64);
        if (tid == 0) *flag = (good >= 110) ? 1 : 0;
    }
    grid.sync();

    const bool bf = (*flag) != 0;

    // ---- phase 1a: node projection (MFMA), grid-stride over 64-row tiles --
    {
        __shared__ u16 Wsh[IN_F * WT_STRIDE];   // 34.8 KB, Wt[c][k]
        for (int i = tid; i < IN_F * IN_F; i += 256) {
            int k = i >> 7, c = i & 127;
            u16 v = bf ? ((const u16*)Wn)[i] : f2bf(((const float*)Wn)[i]);
            Wsh[c * WT_STRIDE + k] = v;
        }
        __syncthreads();

        const int wave = tid >> 6, lane = tid & 63;
        const int m = lane & 15, q = lane >> 4;

        for (int tile = blockIdx.x; tile < N_TILES; tile += gridDim.x) {
            const int row_t = tile * 64 + wave * 16;

            bf16x8 afr[4];
            int arow = row_t + m;
            if (arow >= N_NODES) arow = N_NODES - 1;   // clamp; writes guarded
            if (bf) {
                const u16* hp = (const u16*)h + (size_t)arow * IN_F;
                #pragma unroll
                for (int kt = 0; kt < 4; ++kt)
                    afr[kt] = *(const bf16x8*)(hp + kt * 32 + q * 8);
            } else {
                const float* hp = (const float*)h + (size_t)arow * IN_F;
                #pragma unroll
                for (int kt = 0; kt < 4; ++kt) {
                    bf16x8 t;
                    #pragma unroll
                    for (int j = 0; j < 8; ++j)
                        t[j] = (short)f2bf(hp[kt * 32 + q * 8 + j]);
                    afr[kt] = t;
                }
            }

            for (int ct = 0; ct < 8; ++ct) {   // col tile == head
                f32x4 acc = {0.f, 0.f, 0.f, 0.f};
                #pragma unroll
                for (int kt = 0; kt < 4; ++kt) {
                    bf16x8 bfr = *(const bf16x8*)(Wsh + (ct * 16 + m) * WT_STRIDE
                                                  + kt * 32 + q * 8);
                    acc = __builtin_amdgcn_mfma_f32_16x16x32_bf16(afr[kt], bfr,
                                                                  acc, 0, 0, 0);
                }
                const float asv = ldf(a_srcp, ct * 16 + m, bf);
                const float adv = ldf(a_dstp, ct * 16 + m, bf);
                float v1[4], v2[4];
                #pragma unroll
                for (int r = 0; r < 4; ++r) {
                    int grow = row_t + q * 4 + r;
                    if (grow < N_NODES)
                        ht[(size_t)grow * IN_F + ct * 16 + m] = f2bf(acc[r]);
                    v1[r] = acc[r] * asv;
                    v2[r] = acc[r] * adv;
                }
                #pragma unroll
                for (int o = 1; o < 16; o <<= 1) {
                    #pragma unroll
                    for (int r = 0; r < 4; ++r) {
                        v1[r] += __shfl_xor(v1[r], o, 16);
                        v2[r] += __shfl_xor(v2[r], o, 16);
                    }
                }
                if (m == 0) {
                    #pragma unroll
                    for (int r = 0; r < 4; ++r) {
                        int grow = row_t + q * 4 + r;
                        if (grow < N_NODES) {
                            s_src[grow * HEADS + ct] = v1[r];
                            s_dst[grow * HEADS + ct] = v2[r];
                        }
                    }
                }
            }
        }
    }

    // ---- phase 1b: dst histogram (independent of 1a results) --------------
    for (int t = gidx; t < N_EDGES; t += gsz)
        atomicAdd(&counts[ei[N_EDGES + t]], 1);
    grid.sync();

    // ---- phase 2: segment offsets (order-free allocator) ------------------
    // Wave prefix of counts + ONE atomicAdd per wave. Uniform trip count.
    {
        const int lane = tid & 63;
        const int iters = (N_NODES + gsz - 1) / gsz;
        for (int it = 0; it < iters; ++it) {
            int i = gidx + it * gsz;
            int c = (i < N_NODES) ? counts[i] : 0;
            int pre = c;
            #pragma unroll
            for (int o = 1; o < 64; o <<= 1) {
                int v = __shfl_up(pre, o, 64);
                if (lane >= o) pre += v;
            }
            int wtot = __shfl(pre, 63, 64);
            int base = 0;
            if (lane == 63 && wtot > 0) base = atomicAdd(total, wtot);
            base = __shfl(base, 63, 64);
            if (i < N_NODES) {
                int off = base + pre - c;   // exclusive
                seg_off[i] = off;
                cursor[i]  = off;
            }
        }
    }
    grid.sync();

    // ---- phase 3: scatter edges (packed 8 B payload, ONE store/edge) ------
    for (int t = gidx; t < N_EDGES; t += gsz) {
        int s = ei[t], d = ei[N_EDGES + t];
        int pos = atomicAdd(&cursor[d], 1);
        int2 p;
        p.x = s;
        p.y = __float_as_int(ldf(ef, t, bf));
        edge_s[pos] = p;
    }
}

// ================================================================ aggregate
// One wave per dst node, 4 edge-slots x 16 lanes (4 independent gather
// chains). Lane L of a slot reads ht[src, L*8..L*8+8) (16 B); lanes 0..7
// compute w for heads 0..7; slot partials folded via xor-shuffle (16,32);
// normalize + head-mean (xor 2,4,8) at the end; direct bf16/f32 output.
__global__ __launch_bounds__(256) void aggregate(
    const int* __restrict__ seg_off, const int* __restrict__ counts,
    const int2* __restrict__ edge_s,
    const void* __restrict__ We, const int* __restrict__ flag,
    const float* __restrict__ s_src, const float* __restrict__ s_dst,
    const u16* __restrict__ ht, void* __restrict__ out)
{
    const bool bf = (*flag) != 0;
    int g = (blockIdx.x * 256 + threadIdx.x) >> 6;   // node id (wave)
    if (g >= N_NODES) return;
    const int lane = threadIdx.x & 63;
    const int slot = lane >> 4;     // 0..3
    const int sl   = lane & 15;
    const int myh  = sl >> 1;

    const int off = seg_off[g];
    const int deg = counts[g];

    float sdv = 0.0f, wev = 0.0f;
    if (sl < 8) {
        sdv = s_dst[g * HEADS + sl];
        wev = ldf(We, sl, bf);
    }

    float acc[8];
    #pragma unroll
    for (int j = 0; j < 8; ++j) acc[j] = 0.0f;
    float sw = 0.0f;

    for (int i = slot; i < deg; i += 4) {
        int2 p = edge_s[off + i];
        int src = p.x;
        float w = 0.0f;
        if (sl < 8) {
            float a = s_src[src * HEADS + sl] + sdv + __int_as_float(p.y) * wev;
            a = (a > 0.0f) ? a : 0.2f * a;
            w = __expf(a);
        }
        float wv = __shfl(w, myh, 16);   // head sl>>1 weight, within slot
        bf16x8 v8 = *(const bf16x8*)(ht + (size_t)src * IN_F + sl * 8);
        #pragma unroll
        for (int j = 0; j < 8; ++j)
            acc[j] = fmaf(wv, bf2f((u16)v8[j]), acc[j]);
        sw += wv;
    }

    // fold the 4 slots (lanes differing in bits 4,5)
    #pragma unroll
    for (int o = 16; o < 64; o <<= 1) {
        sw += __shfl_xor(sw, o, 64);
        #pragma unroll
        for (int j = 0; j < 8; ++j)
            acc[j] += __shfl_xor(acc[j], o, 64);
    }

    const float inv = 1.0f / fmaxf(sw, 1e-12f);
    #pragma unroll
    for (int j = 0; j < 8; ++j) acc[j] *= inv;

    // head-mean: sum the 8 same-parity lanes within the 16-lane segment
    #pragma unroll
    for (int o = 2; o < 16; o <<= 1) {
        #pragma unroll
        for (int j = 0; j < 8; ++j)
            acc[j] += __shfl_xor(acc[j], o, 16);
    }

    if (lane < 2) {   // lane 0: feats 0..7, lane 1: feats 8..15
        if (bf) {
            u16* op = (u16*)out + g * OUT_F + lane * 8;
            bf16x8 o8;
            #pragma unroll
            for (int j = 0; j < 8; ++j) o8[j] = (short)f2bf(acc[j] * 0.125f);
            *(bf16x8*)op = o8;
        } else {
            float* op = (float*)out + g * OUT_F + lane * 8;
            #pragma unroll
            for (int j = 0; j < 8; ++j) op[j] = acc[j] * 0.125f;
        }
    }
}

// ==================================================================== launch
extern "C" void kernel_launch(void* const* d_in, const int* in_sizes, int n_in,
                              void* d_out, int out_size, void* d_ws, size_t ws_size,
                              hipStream_t stream) {
    const void* h     = d_in[0];
    const int*  ei    = (const int*)d_in[1];
    const void* efeat = d_in[2];
    const void* Wn    = d_in[3];
    const void* We    = d_in[4];
    const void* a_src = d_in[5];
    const void* a_dst = d_in[6];

    char* ws = (char*)d_ws;
    int*   flag    = (int*)ws;   ws += 128;
    int*   total   = (int*)ws;   ws += 128;
    u16*   ht      = (u16*)ws;   ws += (size_t)N_NODES * IN_F * 2;    // 12.8 MB
    float* s_src   = (float*)ws; ws += (size_t)N_NODES * HEADS * 4;   // 1.6 MB
    float* s_dst   = (float*)ws; ws += (size_t)N_NODES * HEADS * 4;   // 1.6 MB
    int*   counts  = (int*)ws;   ws += (size_t)N_NODES * 4;
    int*   seg_off = (int*)ws;   ws += (size_t)N_NODES * 4;
    int*   cursor  = (int*)ws;   ws += (size_t)N_NODES * 4;
    int2*  edge_s  = (int2*)ws;  ws += (size_t)N_EDGES * 8;           // 6.4 MB

    // cooperative grid: blocks/CU from occupancy (expect 4 via 34.8 KB LDS)
    int perCU = 0;
    if (hipOccupancyMaxActiveBlocksPerMultiprocessor(&perCU, build, 256, 0)
            != hipSuccess || perCU < 1)
        perCU = 2;   // conservative fallback
    int grid_b = perCU * 256;
    if (grid_b > 1024) grid_b = 1024;

    void* args[] = {
        (void*)&h, (void*)&Wn, (void*)&a_src, (void*)&a_dst,
        (void*)&ei, (void*)&efeat,
        (void*)&flag, (void*)&total, (void*)&ht, (void*)&s_src, (void*)&s_dst,
        (void*)&counts, (void*)&seg_off, (void*)&cursor, (void*)&edge_s
    };
    hipLaunchCooperativeKernel((void*)build, dim3(grid_b), dim3(256),
                               args, 0, stream);

    hipLaunchKernelGGL(aggregate, dim3(((size_t)N_NODES * 64 + 255) / 256),
                       dim3(256), 0, stream, seg_off, counts, edge_s, We, flag,
                       s_src, s_dst, ht, d_out);
}

// Round 7
// 264.282 us; speedup vs baseline: 1.5826x; 1.5826x over previous
//
#include <hip/hip_runtime.h>

#define N_NODES 50000
#define N_EDGES 800000
#define IN_F    128
#define HEADS   8
#define OUT_F   16
#define N_TILES ((N_NODES + 63) / 64)   // 782 blocks of 64 rows

typedef unsigned short u16;
typedef __attribute__((ext_vector_type(8))) short bf16x8;   // 4 VGPRs
typedef __attribute__((ext_vector_type(4))) float f32x4;

__device__ __forceinline__ float bf2f(u16 u) {
    return __uint_as_float(((unsigned)u) << 16);
}
__device__ __forceinline__ u16 f2bf(float f) {
    unsigned u = __float_as_uint(f);
    unsigned r = 0x7fffu + ((u >> 16) & 1u);
    return (u16)((u + r) >> 16);
}
// dtype-adaptive float load: bf=true -> buffer is bf16, else fp32
__device__ __forceinline__ float ldf(const void* p, int i, bool bf) {
    return bf ? bf2f(((const u16*)p)[i]) : ((const float*)p)[i];
}

// ---------------------------------------------- K1: zero + dtype probe
__global__ __launch_bounds__(256) void init_probe(
    const void* __restrict__ h, int* __restrict__ flag,
    int* __restrict__ counts, int* __restrict__ total)
{
    int i = blockIdx.x * 256 + threadIdx.x;
    if (i < N_NODES) counts[i] = 0;
    if (i == 0) *total = 0;
    if (blockIdx.x == 0 && threadIdx.x < 64) {
        const u16* u = (const u16*)h;
        int t = threadIdx.x, good = 0;
        #pragma unroll
        for (int j = 0; j < 2; ++j) {
            int e = (u[t * 2 + j] >> 7) & 0xFF;
            good += (e >= 90 && e <= 141) ? 1 : 0;
        }
        #pragma unroll
        for (int o = 32; o; o >>= 1) good += __shfl_down(good, o, 64);
        if (t == 0) *flag = (good >= 110) ? 1 : 0;
    }
}

// ------------------------------- K2: node projection (MFMA) + dst histogram
// proj: one 64-row tile per block. hist: grid-stride tail (independent work,
// overlaps other blocks' proj).
#define WT_STRIDE 136   // bf16 units; 272 B rows: 16B-aligned
__global__ __launch_bounds__(256) void proj_hist(
    const void* __restrict__ h, const void* __restrict__ Wn,
    const void* __restrict__ a_srcp, const void* __restrict__ a_dstp,
    const int* __restrict__ ei, const int* __restrict__ flag,
    u16* __restrict__ ht, float* __restrict__ s_src, float* __restrict__ s_dst,
    int* __restrict__ counts)
{
    const bool bf = (*flag) != 0;
    __shared__ u16 Wsh[IN_F * WT_STRIDE];   // 34.8 KB, Wt[c][k]
    const int tid = threadIdx.x;

    for (int i = tid; i < IN_F * IN_F; i += 256) {
        int k = i >> 7, c = i & 127;
        u16 v = bf ? ((const u16*)Wn)[i] : f2bf(((const float*)Wn)[i]);
        Wsh[c * WT_STRIDE + k] = v;
    }
    __syncthreads();

    const int wave = tid >> 6, lane = tid & 63;
    const int m = lane & 15, q = lane >> 4;
    const int row_t = blockIdx.x * 64 + wave * 16;

    bf16x8 afr[4];
    int arow = row_t + m;
    if (arow >= N_NODES) arow = N_NODES - 1;   // clamp; writes guarded
    if (bf) {
        const u16* hp = (const u16*)h + (size_t)arow * IN_F;
        #pragma unroll
        for (int kt = 0; kt < 4; ++kt)
            afr[kt] = *(const bf16x8*)(hp + kt * 32 + q * 8);
    } else {
        const float* hp = (const float*)h + (size_t)arow * IN_F;
        #pragma unroll
        for (int kt = 0; kt < 4; ++kt) {
            bf16x8 t;
            #pragma unroll
            for (int j = 0; j < 8; ++j) t[j] = (short)f2bf(hp[kt * 32 + q * 8 + j]);
            afr[kt] = t;
        }
    }

    for (int ct = 0; ct < 8; ++ct) {   // col tile == head
        f32x4 acc = {0.f, 0.f, 0.f, 0.f};
        #pragma unroll
        for (int kt = 0; kt < 4; ++kt) {
            bf16x8 bfr = *(const bf16x8*)(Wsh + (ct * 16 + m) * WT_STRIDE
                                          + kt * 32 + q * 8);
            acc = __builtin_amdgcn_mfma_f32_16x16x32_bf16(afr[kt], bfr, acc, 0, 0, 0);
        }
        const float asv = ldf(a_srcp, ct * 16 + m, bf);
        const float adv = ldf(a_dstp, ct * 16 + m, bf);
        float v1[4], v2[4];
        #pragma unroll
        for (int r = 0; r < 4; ++r) {
            int grow = row_t + q * 4 + r;
            if (grow < N_NODES)
                ht[(size_t)grow * IN_F + ct * 16 + m] = f2bf(acc[r]);
            v1[r] = acc[r] * asv;
            v2[r] = acc[r] * adv;
        }
        #pragma unroll
        for (int o = 1; o < 16; o <<= 1) {
            #pragma unroll
            for (int r = 0; r < 4; ++r) {
                v1[r] += __shfl_xor(v1[r], o, 16);
                v2[r] += __shfl_xor(v2[r], o, 16);
            }
        }
        if (m == 0) {
            #pragma unroll
            for (int r = 0; r < 4; ++r) {
                int grow = row_t + q * 4 + r;
                if (grow < N_NODES) {
                    s_src[grow * HEADS + ct] = v1[r];
                    s_dst[grow * HEADS + ct] = v2[r];
                }
            }
        }
    }

    // hist tail: grid-stride over edges
    const int gsz = N_TILES * 256;
    for (int t = blockIdx.x * 256 + tid; t < N_EDGES; t += gsz)
        atomicAdd(&counts[ei[N_EDGES + t]], 1);
}

// ---------------------------------- K3: segment alloc (order-free, tiny)
__global__ __launch_bounds__(256) void alloc_offsets(
    const int* __restrict__ counts, int* __restrict__ seg_off,
    int* __restrict__ cursor, int* __restrict__ total)
{
    int i = blockIdx.x * 256 + threadIdx.x;
    int lane = threadIdx.x & 63;
    int c = (i < N_NODES) ? counts[i] : 0;
    int pre = c;
    #pragma unroll
    for (int o = 1; o < 64; o <<= 1) {
        int v = __shfl_up(pre, o, 64);
        if (lane >= o) pre += v;
    }
    int wtot = __shfl(pre, 63, 64);
    int base = 0;
    if (lane == 63 && wtot > 0) base = atomicAdd(total, wtot);
    base = __shfl(base, 63, 64);
    if (i < N_NODES) {
        int off = base + pre - c;   // exclusive
        seg_off[i] = off;
        cursor[i]  = off;
    }
}

// --------------------------- K4: scatter edges (packed 8 B, ONE store/edge)
__global__ __launch_bounds__(256) void scatter_edges(
    const int* __restrict__ ei, const void* __restrict__ ef,
    const int* __restrict__ flag, int* __restrict__ cursor,
    int2* __restrict__ edge_s)
{
    const bool bf = (*flag) != 0;
    int t = blockIdx.x * 256 + threadIdx.x;
    if (t >= N_EDGES) return;
    int s = ei[t], d = ei[N_EDGES + t];
    int pos = atomicAdd(&cursor[d], 1);
    int2 p;
    p.x = s;
    p.y = __float_as_int(ldf(ef, t, bf));
    edge_s[pos] = p;
}

// -------------------------------------- K5: aggregation (wave per dst node)
// 4 edge-slots x 16 lanes (4 independent gather chains). Lane L of a slot
// reads ht[src, L*8..L*8+8) (16 B); lanes 0..7 compute w for heads 0..7;
// slot partials folded via xor-shuffle (16,32); normalize + head-mean
// (xor 2,4,8); direct bf16/f32 output.
__global__ __launch_bounds__(256) void aggregate(
    const int* __restrict__ seg_off, const int* __restrict__ counts,
    const int2* __restrict__ edge_s,
    const void* __restrict__ We, const int* __restrict__ flag,
    const float* __restrict__ s_src, const float* __restrict__ s_dst,
    const u16* __restrict__ ht, void* __restrict__ out)
{
    const bool bf = (*flag) != 0;
    int g = (blockIdx.x * 256 + threadIdx.x) >> 6;   // node id (wave)
    if (g >= N_NODES) return;
    const int lane = threadIdx.x & 63;
    const int slot = lane >> 4;     // 0..3
    const int sl   = lane & 15;
    const int myh  = sl >> 1;

    const int off = seg_off[g];
    const int deg = counts[g];

    float sdv = 0.0f, wev = 0.0f;
    if (sl < 8) {
        sdv = s_dst[g * HEADS + sl];
        wev = ldf(We, sl, bf);
    }

    float acc[8];
    #pragma unroll
    for (int j = 0; j < 8; ++j) acc[j] = 0.0f;
    float sw = 0.0f;

    for (int i = slot; i < deg; i += 4) {
        int2 p = edge_s[off + i];
        int src = p.x;
        float w = 0.0f;
        if (sl < 8) {
            float a = s_src[src * HEADS + sl] + sdv + __int_as_float(p.y) * wev;
            a = (a > 0.0f) ? a : 0.2f * a;
            w = __expf(a);
        }
        float wv = __shfl(w, myh, 16);   // head sl>>1 weight, within slot
        bf16x8 v8 = *(const bf16x8*)(ht + (size_t)src * IN_F + sl * 8);
        #pragma unroll
        for (int j = 0; j < 8; ++j)
            acc[j] = fmaf(wv, bf2f((u16)v8[j]), acc[j]);
        sw += wv;
    }

    // fold the 4 slots (lanes differing in bits 4,5)
    #pragma unroll
    for (int o = 16; o < 64; o <<= 1) {
        sw += __shfl_xor(sw, o, 64);
        #pragma unroll
        for (int j = 0; j < 8; ++j)
            acc[j] += __shfl_xor(acc[j], o, 64);
    }

    const float inv = 1.0f / fmaxf(sw, 1e-12f);
    #pragma unroll
    for (int j = 0; j < 8; ++j) acc[j] *= inv;

    // head-mean: sum the 8 same-parity lanes within the 16-lane segment
    #pragma unroll
    for (int o = 2; o < 16; o <<= 1) {
        #pragma unroll
        for (int j = 0; j < 8; ++j)
            acc[j] += __shfl_xor(acc[j], o, 16);
    }

    if (lane < 2) {   // lane 0: feats 0..7, lane 1: feats 8..15
        if (bf) {
            u16* op = (u16*)out + g * OUT_F + lane * 8;
            bf16x8 o8;
            #pragma unroll
            for (int j = 0; j < 8; ++j) o8[j] = (short)f2bf(acc[j] * 0.125f);
            *(bf16x8*)op = o8;
        } else {
            float* op = (float*)out + g * OUT_F + lane * 8;
            #pragma unroll
            for (int j = 0; j < 8; ++j) op[j] = acc[j] * 0.125f;
        }
    }
}

// ==================================================================== launch
extern "C" void kernel_launch(void* const* d_in, const int* in_sizes, int n_in,
                              void* d_out, int out_size, void* d_ws, size_t ws_size,
                              hipStream_t stream) {
    const void* h     = d_in[0];
    const int*  ei    = (const int*)d_in[1];
    const void* efeat = d_in[2];
    const void* Wn    = d_in[3];
    const void* We    = d_in[4];
    const void* a_src = d_in[5];
    const void* a_dst = d_in[6];

    char* ws = (char*)d_ws;
    int*   flag    = (int*)ws;   ws += 128;
    int*   total   = (int*)ws;   ws += 128;
    u16*   ht      = (u16*)ws;   ws += (size_t)N_NODES * IN_F * 2;    // 12.8 MB
    float* s_src   = (float*)ws; ws += (size_t)N_NODES * HEADS * 4;   // 1.6 MB
    float* s_dst   = (float*)ws; ws += (size_t)N_NODES * HEADS * 4;   // 1.6 MB
    int*   counts  = (int*)ws;   ws += (size_t)N_NODES * 4;
    int*   seg_off = (int*)ws;   ws += (size_t)N_NODES * 4;
    int*   cursor  = (int*)ws;   ws += (size_t)N_NODES * 4;
    int2*  edge_s  = (int2*)ws;  ws += (size_t)N_EDGES * 8;           // 6.4 MB

    hipLaunchKernelGGL(init_probe, dim3((N_NODES + 255) / 256), dim3(256),
                       0, stream, h, flag, counts, total);
    hipLaunchKernelGGL(proj_hist, dim3(N_TILES), dim3(256),
                       0, stream, h, Wn, a_src, a_dst, ei, flag,
                       ht, s_src, s_dst, counts);
    hipLaunchKernelGGL(alloc_offsets, dim3((N_NODES + 255) / 256), dim3(256),
                       0, stream, counts, seg_off, cursor, total);
    hipLaunchKernelGGL(scatter_edges, dim3((N_EDGES + 255) / 256), dim3(256),
                       0, stream, ei, efeat, flag, cursor, edge_s);
    hipLaunchKernelGGL(aggregate, dim3(((size_t)N_NODES * 64 + 255) / 256),
                       dim3(256), 0, stream, seg_off, counts, edge_s, We, flag,
                       s_src, s_dst, ht, d_out);
}